// Round 1
// baseline (5245.225 us; speedup 1.0000x reference)
//
#include <hip/hip_runtime.h>
#include <math.h>

// Problem constants
#define BATCH 256
#define TT    2048
#define CC    39
#define NBLK  8
#define KK    2
#define NCLS  8
#define TILE  256
#define NTILES (TT / TILE)
#define BN_EPS 1e-5f

// ws layout (in floats)
#define SZ_BUF  ((size_t)BATCH * CC * TT)                    // 20,447,232
#define SZ_SKIP ((size_t)NBLK * 2 * BATCH * CC * NTILES)     // 1,277,952
#define SZ_WF   ((size_t)2 * NBLK * 2 * CC * CC * KK)        // 97,344
#define SZ_BF   ((size_t)2 * NBLK * 2 * CC)                  // 2,496

// ---------------------------------------------------------------------------
// Fold BN (eval) into conv weights/biases for all dirs/blocks/layers.
// wF layout: [dir][blk][layer][co][ci][k]  (same as source, dir-major)
// bF layout: [dir][blk][layer][co]
// ---------------------------------------------------------------------------
__global__ void fold_kernel(const float* __restrict__ fw_w, const float* __restrict__ fw_b,
                            const float* __restrict__ fw_g, const float* __restrict__ fw_be,
                            const float* __restrict__ fw_m, const float* __restrict__ fw_v,
                            const float* __restrict__ bw_w, const float* __restrict__ bw_b,
                            const float* __restrict__ bw_g, const float* __restrict__ bw_be,
                            const float* __restrict__ bw_m, const float* __restrict__ bw_v,
                            float* __restrict__ wF, float* __restrict__ bF) {
    const int WTOT = 2 * NBLK * 2 * CC * CC * KK;
    const int BTOT = 2 * NBLK * 2 * CC;
    int idx = blockIdx.x * blockDim.x + threadIdx.x;
    if (idx < WTOT) {
        int dir = idx / (NBLK * 2 * CC * CC * KK);
        int r   = idx % (NBLK * 2 * CC * CC * KK);   // [blk][layer][co][ci][k]
        int il  = r / (CC * CC * KK);                // blk*2 + layer
        int co  = (r / (CC * KK)) % CC;
        const float* w = dir ? bw_w : fw_w;
        const float* g = dir ? bw_g : fw_g;
        const float* v = dir ? bw_v : fw_v;
        float s = g[il * CC + co] * rsqrtf(v[il * CC + co] + BN_EPS);
        wF[idx] = w[r] * s;
    } else if (idx < WTOT + BTOT) {
        int bidx = idx - WTOT;
        int dir = bidx / (NBLK * 2 * CC);
        int r   = bidx % (NBLK * 2 * CC);            // il*CC + co
        const float* b  = dir ? bw_b  : fw_b;
        const float* g  = dir ? bw_g  : fw_g;
        const float* be = dir ? bw_be : fw_be;
        const float* m  = dir ? bw_m  : fw_m;
        const float* v  = dir ? bw_v  : fw_v;
        float s = g[r] * rsqrtf(v[r] + BN_EPS);
        bF[bidx] = (b[r] - m[r]) * s + be[r];
    }
}

// ---------------------------------------------------------------------------
// Front: transpose [B,T,C] -> [B,C,T] with 1x1 conv (+ optional time reverse)
// ---------------------------------------------------------------------------
__global__ __launch_bounds__(256) void front_kernel(const float* __restrict__ in,
                                                    const float* __restrict__ w,
                                                    const float* __restrict__ bias,
                                                    float* __restrict__ out, int rev) {
    int b = blockIdx.y;
    int t = blockIdx.x * 256 + threadIdx.x;
    int st = rev ? (TT - 1 - t) : t;
    const float* ip = in + ((size_t)b * TT + st) * CC;
    float x[CC];
#pragma unroll
    for (int ci = 0; ci < CC; ++ci) x[ci] = ip[ci];
    float* op = out + (size_t)b * CC * TT + t;
    for (int co = 0; co < CC; ++co) {
        const float* wr = w + co * CC;   // uniform -> s_load
        float acc = bias[co];
#pragma unroll
        for (int ci = 0; ci < CC; ++ci) acc = fmaf(wr[ci], x[ci], acc);
        op[(size_t)co * TT] = acc;
    }
}

// ---------------------------------------------------------------------------
// One Temporal_Aware_Block (eval), fused:
//   y1 = relu(BNconv1(x))  (staged in LDS over [t0-d, t0+TILE))
//   y2 = BNconv2(y1); out = x * sigmoid(y2)
//   partial skip sum per (b, c, tile) written deterministically (no atomics)
// ---------------------------------------------------------------------------
__global__ __launch_bounds__(256) void block_kernel(const float* __restrict__ x,
                                                    float* __restrict__ y,
                                                    const float* __restrict__ wF,  // [2][CC][CC*KK] folded
                                                    const float* __restrict__ bF,  // [2][CC]
                                                    float* __restrict__ skipPart,  // [B][CC][NTILES]
                                                    int d, int writeOut) {
    extern __shared__ float lds[];
    const int span = TILE + d;
    float* y1s     = lds;                  // [CC][span]
    float* skipLds = lds + (size_t)CC * span;  // [CC][4]

    const int b   = blockIdx.y;
    const int t0  = blockIdx.x * TILE;
    const int tid = threadIdx.x;
    const float* xb = x + (size_t)b * CC * TT;

    // ---- stage 1: y1 for positions [t0-d, t0+TILE) ----
    for (int j = tid; j < span; j += 256) {
        int t = t0 - d + j;
        if (t < 0) {
            // zero-pad region (this is conv2's left pad)
#pragma unroll
            for (int co = 0; co < CC; ++co) y1s[(size_t)co * span + j] = 0.f;
            continue;
        }
        float xt[CC], xp[CC];
#pragma unroll
        for (int ci = 0; ci < CC; ++ci) xt[ci] = xb[(size_t)ci * TT + t];
        if (t - d >= 0) {
#pragma unroll
            for (int ci = 0; ci < CC; ++ci) xp[ci] = xb[(size_t)ci * TT + t - d];
        } else {
#pragma unroll
            for (int ci = 0; ci < CC; ++ci) xp[ci] = 0.f;
        }
        for (int co = 0; co < CC; ++co) {
            const float* wr = wF + co * (CC * KK);   // uniform -> s_load
            float acc = bF[co];
#pragma unroll
            for (int ci = 0; ci < CC; ++ci) {
                acc = fmaf(wr[ci * KK + 0], xp[ci], acc);
                acc = fmaf(wr[ci * KK + 1], xt[ci], acc);
            }
            y1s[(size_t)co * span + j] = fmaxf(acc, 0.f);
        }
    }
    __syncthreads();

    // ---- stage 2: y2 + gate at t = t0 + tid ----
    const int t = t0 + tid;
    const int lane = tid & 63;
    const int wave = tid >> 6;
    float y1t[CC], y1p[CC];
#pragma unroll
    for (int ci = 0; ci < CC; ++ci) {
        y1t[ci] = y1s[(size_t)ci * span + tid + d];  // y1 at t
        y1p[ci] = y1s[(size_t)ci * span + tid];      // y1 at t-d (zero-padded)
    }
    const float* wF1 = wF + CC * CC * KK;
    const float* bF1 = bF + CC;
    float* yb = y + (size_t)b * CC * TT;

    for (int co = 0; co < CC; ++co) {
        const float* wr = wF1 + co * (CC * KK);
        float acc = bF1[co];
#pragma unroll
        for (int ci = 0; ci < CC; ++ci) {
            acc = fmaf(wr[ci * KK + 0], y1p[ci], acc);
            acc = fmaf(wr[ci * KK + 1], y1t[ci], acc);
        }
        float sig = 1.0f / (1.0f + __expf(-acc));
        float ov  = xb[(size_t)co * TT + t] * sig;
        if (writeOut) yb[(size_t)co * TT + t] = ov;
        // wave reduce (64 lanes) then stash per-wave partial
        float r = ov;
#pragma unroll
        for (int off = 32; off > 0; off >>= 1) r += __shfl_down(r, off, 64);
        if (lane == 0) skipLds[co * 4 + wave] = r;
    }
    __syncthreads();
    if (tid < CC) {
        float s = skipLds[tid * 4 + 0] + skipLds[tid * 4 + 1] +
                  skipLds[tid * 4 + 2] + skipLds[tid * 4 + 3];
        skipPart[((size_t)b * CC + tid) * NTILES + blockIdx.x] = s;
    }
}

// ---------------------------------------------------------------------------
// Tail: means -> WeightLayer -> classifier -> log_softmax.  One thread per b.
// ---------------------------------------------------------------------------
__global__ __launch_bounds__(256) void tail_kernel(const float* __restrict__ skipPart,
                                                   const float* __restrict__ wl,
                                                   const float* __restrict__ cw,
                                                   const float* __restrict__ cb,
                                                   float* __restrict__ out) {
    int b = threadIdx.x;
    float x2[CC];
#pragma unroll
    for (int c = 0; c < CC; ++c) x2[c] = 0.f;
    for (int i = 0; i < NBLK; ++i) {
        float wli = wl[i] * (1.0f / TT);
        for (int dir = 0; dir < 2; ++dir) {
            const float* sp = skipPart + (((size_t)(i * 2 + dir) * BATCH + b) * CC) * NTILES;
            for (int c = 0; c < CC; ++c) {
                float s = 0.f;
#pragma unroll
                for (int tl = 0; tl < NTILES; ++tl) s += sp[c * NTILES + tl];
                x2[c] = fmaf(s, wli, x2[c]);
            }
        }
    }
    float lg[NCLS];
    float mx = -1e30f;
    for (int o = 0; o < NCLS; ++o) {
        float a = cb[o];
#pragma unroll
        for (int c = 0; c < CC; ++c) a = fmaf(cw[o * CC + c], x2[c], a);
        lg[o] = a;
        mx = fmaxf(mx, a);
    }
    float se = 0.f;
    for (int o = 0; o < NCLS; ++o) se += expf(lg[o] - mx);
    float lse = logf(se) + mx;
    for (int o = 0; o < NCLS; ++o) out[b * NCLS + o] = lg[o] - lse;
}

// ---------------------------------------------------------------------------
extern "C" void kernel_launch(void* const* d_in, const int* in_sizes, int n_in,
                              void* d_out, int out_size, void* d_ws, size_t ws_size,
                              hipStream_t stream) {
    const float* inputs = (const float*)d_in[0];
    const float* c1w    = (const float*)d_in[1];
    const float* c1b    = (const float*)d_in[2];
    const float* fw_w   = (const float*)d_in[3];
    const float* fw_b   = (const float*)d_in[4];
    const float* fw_g   = (const float*)d_in[5];
    const float* fw_be  = (const float*)d_in[6];
    const float* fw_m   = (const float*)d_in[7];
    const float* fw_v   = (const float*)d_in[8];
    const float* bw_w   = (const float*)d_in[9];
    const float* bw_b   = (const float*)d_in[10];
    const float* bw_g   = (const float*)d_in[11];
    const float* bw_be  = (const float*)d_in[12];
    const float* bw_m   = (const float*)d_in[13];
    const float* bw_v   = (const float*)d_in[14];
    const float* wl     = (const float*)d_in[15];
    const float* clsw   = (const float*)d_in[16];
    const float* clsb   = (const float*)d_in[17];

    float* ws   = (float*)d_ws;
    float* bufA = ws;
    float* bufB = ws + SZ_BUF;
    float* skip = ws + 2 * SZ_BUF;
    float* wF   = ws + 2 * SZ_BUF + SZ_SKIP;
    float* bF   = ws + 2 * SZ_BUF + SZ_SKIP + SZ_WF;

    // fold BN into conv weights
    {
        int tot = (int)(SZ_WF + SZ_BF);
        fold_kernel<<<(tot + 255) / 256, 256, 0, stream>>>(
            fw_w, fw_b, fw_g, fw_be, fw_m, fw_v,
            bw_w, bw_b, bw_g, bw_be, bw_m, bw_v, wF, bF);
    }

    for (int dir = 0; dir < 2; ++dir) {
        front_kernel<<<dim3(TT / 256, BATCH), 256, 0, stream>>>(inputs, c1w, c1b, bufA, dir);
        float* cur = bufA;
        float* nxt = bufB;
        for (int i = 0; i < NBLK; ++i) {
            int d = 1 << i;
            int span = TILE + d;
            size_t lds_bytes = ((size_t)CC * span + 4 * CC) * sizeof(float);
            const float* wFi = wF + ((size_t)(dir * NBLK + i) * 2 * CC * CC * KK);
            const float* bFi = bF + ((size_t)(dir * NBLK + i) * 2 * CC);
            float* sp = skip + ((size_t)(i * 2 + dir) * BATCH * CC * NTILES);
            block_kernel<<<dim3(NTILES, BATCH), 256, lds_bytes, stream>>>(
                cur, nxt, wFi, bFi, sp, d, (i < NBLK - 1) ? 1 : 0);
            float* tmp = cur; cur = nxt; nxt = tmp;
        }
    }

    tail_kernel<<<1, 256, 0, stream>>>(skip, wl, clsw, clsb, (float*)d_out);
}

// Round 2
// 3355.872 us; speedup vs baseline: 1.5630x; 1.5630x over previous
//
#include <hip/hip_runtime.h>
#include <math.h>

// Problem constants
#define BATCH 256
#define TT    2048
#define CC    39
#define NBLK  8
#define KK    2
#define NCLS  8
#define TILE  256
#define NTILES (TT / TILE)
#define BN_EPS 1e-5f
#define CHUNK 13            // CC = 3 * CHUNK
#define STASH 257           // stash stride (odd -> bank spread)

// ws layout (in floats)
#define SZ_BUF  ((size_t)BATCH * CC * TT)                    // 20,447,232
#define SZ_SKIP ((size_t)NBLK * 2 * BATCH * CC * NTILES)     // 131,072*... per-dir/blk partials
#define SZ_WF   ((size_t)2 * NBLK * 2 * CC * CC * KK)        // transposed folded weights
#define SZ_BF   ((size_t)2 * NBLK * 2 * CC)
#define SZ_W1   ((size_t)CC * CC)                            // transposed 1x1 weights

// ---------------------------------------------------------------------------
// Fold BN into conv weights, TRANSPOSED to [ci][k][co] (contiguous co rows),
// plus transposed 1x1 front weights [ci][co].
// ---------------------------------------------------------------------------
__global__ void fold_kernel(const float* __restrict__ fw_w, const float* __restrict__ fw_b,
                            const float* __restrict__ fw_g, const float* __restrict__ fw_be,
                            const float* __restrict__ fw_m, const float* __restrict__ fw_v,
                            const float* __restrict__ bw_w, const float* __restrict__ bw_b,
                            const float* __restrict__ bw_g, const float* __restrict__ bw_be,
                            const float* __restrict__ bw_m, const float* __restrict__ bw_v,
                            const float* __restrict__ c1w,
                            float* __restrict__ wT, float* __restrict__ bF,
                            float* __restrict__ w1T) {
    const int WTOT = 2 * NBLK * 2 * CC * CC * KK;
    const int BTOT = 2 * NBLK * 2 * CC;
    int idx = blockIdx.x * blockDim.x + threadIdx.x;
    if (idx < WTOT) {
        int dir = idx / (NBLK * 2 * CC * CC * KK);
        int r   = idx % (NBLK * 2 * CC * CC * KK);
        int il  = r / (CC * CC * KK);                 // blk*2 + layer
        int rr  = r % (CC * CC * KK);                 // (ci*KK + k)*CC + co
        int ci  = rr / (KK * CC);
        int k   = (rr / CC) % KK;
        int co  = rr % CC;
        const float* w = dir ? bw_w : fw_w;
        const float* g = dir ? bw_g : fw_g;
        const float* v = dir ? bw_v : fw_v;
        float s = g[il * CC + co] * rsqrtf(v[il * CC + co] + BN_EPS);
        wT[idx] = w[(((size_t)il * CC + co) * CC + ci) * KK + k] * s;
    } else if (idx < WTOT + BTOT) {
        int bidx = idx - WTOT;
        int dir = bidx / (NBLK * 2 * CC);
        int r   = bidx % (NBLK * 2 * CC);             // il*CC + co
        const float* b  = dir ? bw_b  : fw_b;
        const float* g  = dir ? bw_g  : fw_g;
        const float* be = dir ? bw_be : fw_be;
        const float* m  = dir ? bw_m  : fw_m;
        const float* v  = dir ? bw_v  : fw_v;
        float s = g[r] * rsqrtf(v[r] + BN_EPS);
        bF[bidx] = (b[r] - m[r]) * s + be[r];
    } else if (idx < WTOT + BTOT + CC * CC) {
        int r  = idx - WTOT - BTOT;                   // ci*CC + co
        int ci = r / CC, co = r % CC;
        w1T[r] = c1w[co * CC + ci];                   // src (C,C,1): [co][ci]
    }
}

// ---------------------------------------------------------------------------
// Front: [B,T,C] -> [B,C,T] with 1x1 conv (+ optional time reverse).
// ci-chunked, co-inner (39 independent accumulators), weights via s_load.
// ---------------------------------------------------------------------------
__global__ __launch_bounds__(256) void front_kernel(const float* __restrict__ in,
                                                    const float* __restrict__ w1T, // [ci][co]
                                                    const float* __restrict__ bias,
                                                    float* __restrict__ out, int rev) {
    int b = blockIdx.y;
    int t = blockIdx.x * 256 + threadIdx.x;
    int st = rev ? (TT - 1 - t) : t;
    const float* ip = in + ((size_t)b * TT + st) * CC;
    float acc[CC];
#pragma unroll
    for (int co = 0; co < CC; ++co) acc[co] = bias[co];
    for (int c0 = 0; c0 < CC; c0 += CHUNK) {
        float xv[CHUNK];
#pragma unroll
        for (int u = 0; u < CHUNK; ++u) xv[u] = ip[c0 + u];
#pragma unroll
        for (int u = 0; u < CHUNK; ++u) {
            const float* wr = w1T + (size_t)(c0 + u) * CC;
#pragma unroll
            for (int co = 0; co < CC; ++co) acc[co] = fmaf(wr[co], xv[u], acc[co]);
        }
    }
    float* op = out + (size_t)b * CC * TT + t;
#pragma unroll
    for (int co = 0; co < CC; ++co) op[(size_t)co * TT] = acc[co];
}

// ---------------------------------------------------------------------------
// One Temporal_Aware_Block, fused. ci-chunked / co-inner register blocking.
// ---------------------------------------------------------------------------
__global__ __launch_bounds__(256) void block_kernel(const float* __restrict__ x,
                                                    float* __restrict__ y,
                                                    const float* __restrict__ wT, // [2][ci][k][co]
                                                    const float* __restrict__ bF, // [2][co]
                                                    float* __restrict__ skipPart, // [B][CC][NTILES]
                                                    int d, int writeOut) {
    extern __shared__ float lds[];
    const int span = TILE + d;
    float* y1s = lds;                       // [CC][span]

    const int b   = blockIdx.y;
    const int t0  = blockIdx.x * TILE;
    const int tid = threadIdx.x;
    const float* xb = x + (size_t)b * CC * TT;

    // ---- stage 1: y1 = relu(conv1(x)) over [t0-d, t0+TILE) ----
    for (int j = tid; j < span; j += 256) {
        int t = t0 - d + j;
        if (t < 0) {
#pragma unroll
            for (int co = 0; co < CC; ++co) y1s[(size_t)co * span + j] = 0.f;
            continue;
        }
        const int hasP = (t - d >= 0);
        float acc[CC];
#pragma unroll
        for (int co = 0; co < CC; ++co) acc[co] = bF[co];
        for (int c0 = 0; c0 < CC; c0 += CHUNK) {
            float xt_[CHUNK], xp_[CHUNK];
#pragma unroll
            for (int u = 0; u < CHUNK; ++u) {
                int ci = c0 + u;
                xt_[u] = xb[(size_t)ci * TT + t];
                xp_[u] = hasP ? xb[(size_t)ci * TT + t - d] : 0.f;
            }
#pragma unroll
            for (int u = 0; u < CHUNK; ++u) {
                const float* wr0 = wT + (size_t)((c0 + u) * KK + 0) * CC;
                const float* wr1 = wT + (size_t)((c0 + u) * KK + 1) * CC;
#pragma unroll
                for (int co = 0; co < CC; ++co) {
                    acc[co] = fmaf(wr0[co], xp_[u], acc[co]);
                    acc[co] = fmaf(wr1[co], xt_[u], acc[co]);
                }
            }
        }
#pragma unroll
        for (int co = 0; co < CC; ++co) y1s[(size_t)co * span + j] = fmaxf(acc[co], 0.f);
    }
    __syncthreads();

    // ---- stage 2: y2 = conv2(y1); out = x * sigmoid(y2) at t = t0+tid ----
    const float* w1  = wT + (size_t)CC * CC * KK;
    const float* bF1 = bF + CC;
    const int t = t0 + tid;
    float acc[CC];
#pragma unroll
    for (int co = 0; co < CC; ++co) acc[co] = bF1[co];
    for (int c0 = 0; c0 < CC; c0 += CHUNK) {
        float y1t_[CHUNK], y1p_[CHUNK];
#pragma unroll
        for (int u = 0; u < CHUNK; ++u) {
            y1p_[u] = y1s[(size_t)(c0 + u) * span + tid];       // t - d (padded)
            y1t_[u] = y1s[(size_t)(c0 + u) * span + tid + d];   // t
        }
#pragma unroll
        for (int u = 0; u < CHUNK; ++u) {
            const float* wr0 = w1 + (size_t)((c0 + u) * KK + 0) * CC;
            const float* wr1 = w1 + (size_t)((c0 + u) * KK + 1) * CC;
#pragma unroll
            for (int co = 0; co < CC; ++co) {
                acc[co] = fmaf(wr0[co], y1p_[u], acc[co]);
                acc[co] = fmaf(wr1[co], y1t_[u], acc[co]);
            }
        }
    }
    float* yb = y + (size_t)b * CC * TT;
#pragma unroll
    for (int co = 0; co < CC; ++co) {
        float sig = 1.0f / (1.0f + __expf(-acc[co]));
        acc[co] = xb[(size_t)co * TT + t] * sig;      // gated output
        if (writeOut) yb[(size_t)co * TT + t] = acc[co];
    }
    __syncthreads();   // all y1 reads done; reuse LDS as [CC][STASH] stash

    float* st = lds;
#pragma unroll
    for (int co = 0; co < CC; ++co) st[co * STASH + tid] = acc[co];
    __syncthreads();

    if (tid < CC * 4) {
        int co = tid >> 2, seg = tid & 3;
        float s = 0.f;
        const float* row = st + co * STASH + seg * 64;
#pragma unroll 8
        for (int k = 0; k < 64; ++k) s += row[k];
        s += __shfl_down(s, 2, 4);
        s += __shfl_down(s, 1, 4);
        if (seg == 0)
            skipPart[((size_t)b * CC + co) * NTILES + blockIdx.x] = s;
    }
}

// ---------------------------------------------------------------------------
// Tail: means -> WeightLayer -> classifier -> log_softmax. Block per batch.
// ---------------------------------------------------------------------------
__global__ __launch_bounds__(64) void tail_kernel(const float* __restrict__ skipPart,
                                                  const float* __restrict__ wl,
                                                  const float* __restrict__ cw,
                                                  const float* __restrict__ cb,
                                                  float* __restrict__ out) {
    __shared__ float xs[CC];
    int b = blockIdx.x;
    int c = threadIdx.x;
    if (c < CC) {
        float x2 = 0.f;
        for (int i = 0; i < NBLK; ++i) {
            float wli = wl[i] * (1.0f / TT);
            for (int dir = 0; dir < 2; ++dir) {
                const float* sp = skipPart +
                    (((size_t)(i * 2 + dir) * BATCH + b) * CC + c) * NTILES;
                float s = 0.f;
#pragma unroll
                for (int tl = 0; tl < NTILES; ++tl) s += sp[tl];
                x2 = fmaf(s, wli, x2);
            }
        }
        xs[c] = x2;
    }
    __syncthreads();
    if (threadIdx.x == 0) {
        float lg[NCLS];
        float mx = -1e30f;
        for (int o = 0; o < NCLS; ++o) {
            float a = cb[o];
#pragma unroll
            for (int cc = 0; cc < CC; ++cc) a = fmaf(cw[o * CC + cc], xs[cc], a);
            lg[o] = a;
            mx = fmaxf(mx, a);
        }
        float se = 0.f;
        for (int o = 0; o < NCLS; ++o) se += expf(lg[o] - mx);
        float lse = logf(se) + mx;
        for (int o = 0; o < NCLS; ++o) out[b * NCLS + o] = lg[o] - lse;
    }
}

// ---------------------------------------------------------------------------
extern "C" void kernel_launch(void* const* d_in, const int* in_sizes, int n_in,
                              void* d_out, int out_size, void* d_ws, size_t ws_size,
                              hipStream_t stream) {
    const float* inputs = (const float*)d_in[0];
    const float* c1w    = (const float*)d_in[1];
    const float* c1b    = (const float*)d_in[2];
    const float* fw_w   = (const float*)d_in[3];
    const float* fw_b   = (const float*)d_in[4];
    const float* fw_g   = (const float*)d_in[5];
    const float* fw_be  = (const float*)d_in[6];
    const float* fw_m   = (const float*)d_in[7];
    const float* fw_v   = (const float*)d_in[8];
    const float* bw_w   = (const float*)d_in[9];
    const float* bw_b   = (const float*)d_in[10];
    const float* bw_g   = (const float*)d_in[11];
    const float* bw_be  = (const float*)d_in[12];
    const float* bw_m   = (const float*)d_in[13];
    const float* bw_v   = (const float*)d_in[14];
    const float* wl     = (const float*)d_in[15];
    const float* clsw   = (const float*)d_in[16];
    const float* clsb   = (const float*)d_in[17];

    float* ws   = (float*)d_ws;
    float* bufA = ws;
    float* bufB = ws + SZ_BUF;
    float* skip = ws + 2 * SZ_BUF;
    float* wT   = ws + 2 * SZ_BUF + SZ_SKIP;
    float* bF   = wT + SZ_WF;
    float* w1T  = bF + SZ_BF;

    {
        int tot = (int)(SZ_WF + SZ_BF + SZ_W1);
        fold_kernel<<<(tot + 255) / 256, 256, 0, stream>>>(
            fw_w, fw_b, fw_g, fw_be, fw_m, fw_v,
            bw_w, bw_b, bw_g, bw_be, bw_m, bw_v, c1w, wT, bF, w1T);
    }

    for (int dir = 0; dir < 2; ++dir) {
        front_kernel<<<dim3(TT / 256, BATCH), 256, 0, stream>>>(inputs, w1T, c1b, bufA, dir);
        float* cur = bufA;
        float* nxt = bufB;
        for (int i = 0; i < NBLK; ++i) {
            int d = 1 << i;
            int span = TILE + d;
            size_t lds_bytes = (size_t)CC * span * sizeof(float);
            const float* wTi = wT + ((size_t)(dir * NBLK + i) * 2 * CC * CC * KK);
            const float* bFi = bF + ((size_t)(dir * NBLK + i) * 2 * CC);
            float* sp = skip + ((size_t)(i * 2 + dir) * BATCH * CC * NTILES);
            block_kernel<<<dim3(NTILES, BATCH), 256, lds_bytes, stream>>>(
                cur, nxt, wTi, bFi, sp, d, (i < NBLK - 1) ? 1 : 0);
            float* tmp = cur; cur = nxt; nxt = tmp;
        }
    }

    tail_kernel<<<BATCH, 64, 0, stream>>>(skip, wl, clsw, clsb, (float*)d_out);
}

// Round 3
// 657.905 us; speedup vs baseline: 7.9726x; 5.1008x over previous
//
#include <hip/hip_runtime.h>
#include <math.h>

// Problem constants
#define BATCH 256
#define TT    2048
#define CC    39
#define CP    40        // padded channel stride (bf16) in carried buffers / LDS rows
#define NBLK  8
#define KK    2
#define NCLS  8
#define BN_EPS 1e-5f

typedef __attribute__((ext_vector_type(8))) short short8;
typedef __attribute__((ext_vector_type(4))) float floatx4;

__device__ __forceinline__ unsigned short f2b(float f) {
    union { float f; unsigned u; } v; v.f = f;
    unsigned r = v.u + 0x7FFF + ((v.u >> 16) & 1);   // RNE
    return (unsigned short)(r >> 16);
}
__device__ __forceinline__ float b2f(unsigned short h) {
    union { unsigned u; float f; } v; v.u = ((unsigned)h) << 16;
    return v.f;
}

// Fragment-array sizes
#define WFB_PER_BLKDIR (2*2*2*3*512)                 // layer,p,s,n,lane,reg = 12288
#define WFB_TOTAL      (2*NBLK*WFB_PER_BLKDIR)       // 196608*... = 393216
#define BFB_TOTAL      (2*NBLK*2*48)                 // 1536
#define WFF_TOTAL      (2*3*512)                     // 3072
#define BFF_TOTAL      48

// ---------------------------------------------------------------------------
// Fold BN into conv weights and bake EVERYTHING into MFMA per-lane fragment
// layout: wfb[dir][blk][layer][p][s][n][lane][reg] (bf16), biases padded to 48.
// Front 1x1 weights -> wff[s][n][lane][reg], bias bff[48].
// k-enumeration: ci = s*32 + (lane>>4)*8 + reg  (same map used for A reads).
// ---------------------------------------------------------------------------
__global__ void fold_kernel(const float* __restrict__ fw_w, const float* __restrict__ fw_b,
                            const float* __restrict__ fw_g, const float* __restrict__ fw_be,
                            const float* __restrict__ fw_m, const float* __restrict__ fw_v,
                            const float* __restrict__ bw_w, const float* __restrict__ bw_b,
                            const float* __restrict__ bw_g, const float* __restrict__ bw_be,
                            const float* __restrict__ bw_m, const float* __restrict__ bw_v,
                            const float* __restrict__ c1w, const float* __restrict__ c1b,
                            unsigned short* __restrict__ wfb, float* __restrict__ bfb,
                            unsigned short* __restrict__ wff, float* __restrict__ bff) {
    int idx = blockIdx.x * blockDim.x + threadIdx.x;
    if (idx < WFB_TOTAL) {
        int i = idx;
        int reg = i & 7;  i >>= 3;
        int lane = i & 63; i >>= 6;
        int n = i % 3;     i /= 3;
        int s = i & 1;     i >>= 1;
        int p = i & 1;     i >>= 1;
        int layer = i & 1; i >>= 1;
        int blk = i & 7;   i >>= 3;
        int dir = i;
        int co = n * 16 + (lane & 15);
        int ci = s * 32 + ((lane >> 4) << 3) + reg;
        float val = 0.f;
        if (co < CC && ci < CC) {
            const float* w = dir ? bw_w : fw_w;
            const float* g = dir ? bw_g : fw_g;
            const float* v = dir ? bw_v : fw_v;
            int il = blk * 2 + layer;
            float sc = g[il * CC + co] * rsqrtf(v[il * CC + co] + BN_EPS);
            val = w[((size_t)(il * CC + co) * CC + ci) * KK + p] * sc;
        }
        wfb[idx] = f2b(val);
        return;
    }
    idx -= WFB_TOTAL;
    if (idx < BFB_TOTAL) {
        int co = idx % 48;
        int i = idx / 48;
        int layer = i & 1; i >>= 1;
        int blk = i & 7;   i >>= 3;
        int dir = i;
        float val = 0.f;
        if (co < CC) {
            const float* b  = dir ? bw_b  : fw_b;
            const float* g  = dir ? bw_g  : fw_g;
            const float* be = dir ? bw_be : fw_be;
            const float* m  = dir ? bw_m  : fw_m;
            const float* v  = dir ? bw_v  : fw_v;
            int r = (blk * 2 + layer) * CC + co;
            float sc = g[r] * rsqrtf(v[r] + BN_EPS);
            val = (b[r] - m[r]) * sc + be[r];
        }
        bfb[idx] = val;
        return;
    }
    idx -= BFB_TOTAL;
    if (idx < WFF_TOTAL) {
        int i = idx;
        int reg = i & 7;  i >>= 3;
        int lane = i & 63; i >>= 6;
        int n = i % 3;     i /= 3;
        int s = i;         // 0..1
        int co = n * 16 + (lane & 15);
        int ci = s * 32 + ((lane >> 4) << 3) + reg;
        float val = (co < CC && ci < CC) ? c1w[co * CC + ci] : 0.f;
        wff[idx] = f2b(val);
        return;
    }
    idx -= WFF_TOTAL;
    if (idx < BFF_TOTAL) {
        bff[idx] = (idx < CC) ? c1b[idx] : 0.f;
    }
}

// ---------------------------------------------------------------------------
// Front: [B,T,C] f32 -> carried [dir][B][T][CP] bf16 via 1x1 conv (MFMA).
// ---------------------------------------------------------------------------
__global__ __launch_bounds__(256) void front_mfma(const float* __restrict__ in,
                                                  const unsigned short* __restrict__ wf,
                                                  const float* __restrict__ bias,
                                                  unsigned short* __restrict__ out) {
    __shared__ unsigned short xt[256 * CP + 32];
    const int dir = blockIdx.z, b = blockIdx.y, t0 = blockIdx.x * 256;
    const int tid = threadIdx.x, lane = tid & 63, wave = tid >> 6;
    const int stmin = dir ? (TT - t0 - 256) : t0;
    const float* src = in + ((size_t)b * TT + stmin) * CC;

    // copy + convert [256][39] f32 -> LDS [256][CP] bf16 (source time order)
    for (int e = tid; e < 256 * CC; e += 256) {
        int r = e / CC, c = e - r * CC;
        xt[r * CP + c] = f2b(src[e]);
    }
    if (tid < 256) xt[tid * CP + CC] = 0;                 // pad col 39
    if (tid < 32)  xt[256 * CP + tid] = 0;                // slack
    __syncthreads();

    short8 Wf[2][3];
#pragma unroll
    for (int s = 0; s < 2; ++s)
#pragma unroll
        for (int n = 0; n < 3; ++n)
            Wf[s][n] = *(const short8*)(wf + (((size_t)(s * 3 + n) * 64 + lane) << 3));
    float bias_n[3];
#pragma unroll
    for (int n = 0; n < 3; ++n) bias_n[n] = bias[n * 16 + (lane & 15)];

    for (int mt = wave; mt < 16; mt += 4) {
        int j0 = mt << 4;
        floatx4 acc[3];
#pragma unroll
        for (int n = 0; n < 3; ++n) acc[n] = floatx4{bias_n[n], bias_n[n], bias_n[n], bias_n[n]};
#pragma unroll
        for (int s = 0; s < 2; ++s) {
            short8 A = *(const short8*)(xt + (j0 + (lane & 15)) * CP + s * 32 + ((lane >> 4) << 3));
#pragma unroll
            for (int n = 0; n < 3; ++n)
                acc[n] = __builtin_amdgcn_mfma_f32_16x16x32_bf16(A, Wf[s][n], acc[n], 0, 0, 0);
        }
#pragma unroll
        for (int n = 0; n < 3; ++n) {
            int col = n * 16 + (lane & 15);
            if (col < CP) {
#pragma unroll
                for (int j = 0; j < 4; ++j) {
                    int r = j0 + ((lane >> 4) << 2) + j;
                    int t = dir ? (t0 + 255 - r) : (t0 + r);
                    out[((size_t)(dir * BATCH + b) * TT + t) * CP + col] = f2b(acc[n][j]);
                }
            }
        }
    }
}

// ---------------------------------------------------------------------------
// One Temporal_Aware_Block, fused, MFMA:
//   stage1: y1 = relu(BNconv1(x)) into LDS over [t0-d, t0+Tt)
//   stage2: y2 = BNconv2(y1); out = x * sigmoid(y2); per-WG skip partials.
// ---------------------------------------------------------------------------
__global__ __launch_bounds__(256) void block_mfma(const unsigned short* __restrict__ xg,
                                                  unsigned short* __restrict__ yg,
                                                  const unsigned short* __restrict__ wf_all,
                                                  const float* __restrict__ bf_all,
                                                  float* __restrict__ skipPart,
                                                  int d, int blk, int Tt, int writeOut) {
    extern __shared__ char ldsraw[];
    const int dir = blockIdx.z, b = blockIdx.y, tile = blockIdx.x;
    const int t0 = tile * Tt;
    const int tid = threadIdx.x, lane = tid & 63, wave = tid >> 6;
    const int rows_x = Tt + 2 * d;
    const int M1 = (Tt + d + 15) >> 4;
    const int rows_y1 = M1 << 4;
    const int rows_real = Tt + d;

    unsigned short* xt = (unsigned short*)ldsraw;             // [rows_x][CP] +32 slack
    unsigned short* y1 = xt + rows_x * CP + 32;               // [rows_y1][CP] +32 slack
    float* stash = (float*)(y1 + rows_y1 * CP + 32);          // [4][48]

    const size_t cbase = (size_t)(dir * BATCH + b) * TT * CP;
    const unsigned short* wf = wf_all + (size_t)(dir * NBLK + blk) * WFB_PER_BLKDIR;
    const float* bf = bf_all + (size_t)(dir * NBLK + blk) * 96;

    // ---- load x tile rows [t0-2d, t0+Tt) ----
    {
        const uint4* gsrc = (const uint4*)(xg + cbase);
        uint4* ldst = (uint4*)xt;
        int base_t = t0 - 2 * d;
        int nch = rows_x * 5;                                  // 16B chunks (80B rows)
        for (int c = tid; c < nch; c += 256) {
            int row = c / 5;
            int t = base_t + row;
            uint4 v;
            if (t < 0) { v.x = v.y = v.z = v.w = 0u; }
            else       { v = gsrc[(size_t)t * 5 + (c - row * 5)]; }
            ldst[c] = v;
        }
        if (tid < 16) ((unsigned*)(xt + rows_x * CP))[tid] = 0;       // xt slack
        if (tid >= 16 && tid < 32) ((unsigned*)(y1 + rows_y1 * CP))[tid - 16] = 0; // y1 slack
    }
    __syncthreads();

    // ---- stage 1 ----
    short8 Wf[2][2][3];
#pragma unroll
    for (int p = 0; p < 2; ++p)
#pragma unroll
        for (int s = 0; s < 2; ++s)
#pragma unroll
            for (int n = 0; n < 3; ++n)
                Wf[p][s][n] = *(const short8*)(wf + (((size_t)(((0 * 2 + p) * 2 + s) * 3 + n) * 64 + lane) << 3));
    float bias0[3];
#pragma unroll
    for (int n = 0; n < 3; ++n) bias0[n] = bf[n * 16 + (lane & 15)];

    for (int mt = wave; mt < M1; mt += 4) {
        int j0 = mt << 4;
        floatx4 acc[3];
#pragma unroll
        for (int n = 0; n < 3; ++n) acc[n] = floatx4{bias0[n], bias0[n], bias0[n], bias0[n]};
#pragma unroll
        for (int p = 0; p < 2; ++p) {
            int rbase = j0 + (lane & 15) + (p ? d : 0);
#pragma unroll
            for (int s = 0; s < 2; ++s) {
                short8 A = *(const short8*)(xt + rbase * CP + s * 32 + ((lane >> 4) << 3));
#pragma unroll
                for (int n = 0; n < 3; ++n)
                    acc[n] = __builtin_amdgcn_mfma_f32_16x16x32_bf16(A, Wf[p][s][n], acc[n], 0, 0, 0);
            }
        }
#pragma unroll
        for (int n = 0; n < 3; ++n) {
            int col = n * 16 + (lane & 15);
            if (col < CP) {
#pragma unroll
                for (int j = 0; j < 4; ++j) {
                    int r = j0 + ((lane >> 4) << 2) + j;
                    int t = t0 - d + r;
                    float v = fmaxf(acc[n][j], 0.f);
                    if (t < 0 || r >= rows_real) v = 0.f;      // causal pad + pad rows exact 0
                    y1[r * CP + col] = f2b(v);
                }
            }
        }
    }
    __syncthreads();

    // ---- stage 2 ----
#pragma unroll
    for (int p = 0; p < 2; ++p)
#pragma unroll
        for (int s = 0; s < 2; ++s)
#pragma unroll
            for (int n = 0; n < 3; ++n)
                Wf[p][s][n] = *(const short8*)(wf + (((size_t)(((1 * 2 + p) * 2 + s) * 3 + n) * 64 + lane) << 3));
    float bias1[3];
#pragma unroll
    for (int n = 0; n < 3; ++n) bias1[n] = bf[48 + n * 16 + (lane & 15)];

    float sums[3] = {0.f, 0.f, 0.f};
    const int M2w = Tt >> 6;                                   // m-tiles per wave
    for (int mi = 0; mi < M2w; ++mi) {
        int j0 = (wave * M2w + mi) << 4;
        floatx4 acc[3];
#pragma unroll
        for (int n = 0; n < 3; ++n) acc[n] = floatx4{bias1[n], bias1[n], bias1[n], bias1[n]};
#pragma unroll
        for (int p = 0; p < 2; ++p) {
            int rbase = j0 + (lane & 15) + (p ? d : 0);        // p=0: y1[t-d] row r; p=1: row r+d
#pragma unroll
            for (int s = 0; s < 2; ++s) {
                short8 A = *(const short8*)(y1 + rbase * CP + s * 32 + ((lane >> 4) << 3));
#pragma unroll
                for (int n = 0; n < 3; ++n)
                    acc[n] = __builtin_amdgcn_mfma_f32_16x16x32_bf16(A, Wf[p][s][n], acc[n], 0, 0, 0);
            }
        }
#pragma unroll
        for (int n = 0; n < 3; ++n) {
            int col = n * 16 + (lane & 15);
#pragma unroll
            for (int j = 0; j < 4; ++j) {
                int r = j0 + ((lane >> 4) << 2) + j;
                float sig = 1.f / (1.f + __expf(-acc[n][j]));
                float xv = b2f(xt[(r + 2 * d) * CP + col]);    // col>=CP reads next row: finite, unused
                float g = xv * sig;
                if (writeOut && col < CP)
                    yg[cbase + (size_t)(t0 + r) * CP + col] = f2b(g);
                sums[n] += g;
            }
        }
    }
#pragma unroll
    for (int n = 0; n < 3; ++n) {
        sums[n] += __shfl_xor(sums[n], 16, 64);
        sums[n] += __shfl_xor(sums[n], 32, 64);
    }
    if (lane < 16) {
#pragma unroll
        for (int n = 0; n < 3; ++n) stash[wave * 48 + n * 16 + lane] = sums[n];
    }
    __syncthreads();
    if (tid < CC) {
        float s = stash[tid] + stash[48 + tid] + stash[96 + tid] + stash[144 + tid];
        skipPart[(((size_t)(blk * 2 + dir) * BATCH + b) * CC + tid) * 16 + tile] = s;
    }
}

// ---------------------------------------------------------------------------
// Tail: means -> WeightLayer -> classifier -> log_softmax. Block per batch.
// ---------------------------------------------------------------------------
__global__ __launch_bounds__(64) void tail_kernel(const float* __restrict__ skipPart,
                                                  const float* __restrict__ wl,
                                                  const float* __restrict__ cw,
                                                  const float* __restrict__ cb,
                                                  float* __restrict__ out) {
    __shared__ float xs[CC];
    int b = blockIdx.x;
    int c = threadIdx.x;
    if (c < CC) {
        float x2 = 0.f;
        for (int i = 0; i < NBLK; ++i) {
            float wli = wl[i] * (1.0f / TT);
            int nt = (i == NBLK - 1) ? 16 : 8;
            for (int dirn = 0; dirn < 2; ++dirn) {
                const float* sp = skipPart + (((size_t)(i * 2 + dirn) * BATCH + b) * CC + c) * 16;
                float s = 0.f;
                for (int tl = 0; tl < nt; ++tl) s += sp[tl];
                x2 = fmaf(s, wli, x2);
            }
        }
        xs[c] = x2;
    }
    __syncthreads();
    if (threadIdx.x == 0) {
        float lg[NCLS];
        float mx = -1e30f;
        for (int o = 0; o < NCLS; ++o) {
            float a = cb[o];
#pragma unroll
            for (int cc2 = 0; cc2 < CC; ++cc2) a = fmaf(cw[o * CC + cc2], xs[cc2], a);
            lg[o] = a;
            mx = fmaxf(mx, a);
        }
        float se = 0.f;
        for (int o = 0; o < NCLS; ++o) se += expf(lg[o] - mx);
        float lse = logf(se) + mx;
        for (int o = 0; o < NCLS; ++o) out[b * NCLS + o] = lg[o] - lse;
    }
}

// ---------------------------------------------------------------------------
extern "C" void kernel_launch(void* const* d_in, const int* in_sizes, int n_in,
                              void* d_out, int out_size, void* d_ws, size_t ws_size,
                              hipStream_t stream) {
    const float* inputs = (const float*)d_in[0];
    const float* c1w    = (const float*)d_in[1];
    const float* c1b    = (const float*)d_in[2];
    const float* fw_w   = (const float*)d_in[3];
    const float* fw_b   = (const float*)d_in[4];
    const float* fw_g   = (const float*)d_in[5];
    const float* fw_be  = (const float*)d_in[6];
    const float* fw_m   = (const float*)d_in[7];
    const float* fw_v   = (const float*)d_in[8];
    const float* bw_w   = (const float*)d_in[9];
    const float* bw_b   = (const float*)d_in[10];
    const float* bw_g   = (const float*)d_in[11];
    const float* bw_be  = (const float*)d_in[12];
    const float* bw_m   = (const float*)d_in[13];
    const float* bw_v   = (const float*)d_in[14];
    const float* wl     = (const float*)d_in[15];
    const float* clsw   = (const float*)d_in[16];
    const float* clsb   = (const float*)d_in[17];

    const size_t bufsz = (size_t)2 * BATCH * TT * CP;          // ushorts
    unsigned short* buf0 = (unsigned short*)d_ws;
    unsigned short* buf1 = buf0 + bufsz;
    float* skip = (float*)(buf1 + bufsz);
    const size_t skipsz = (size_t)NBLK * 2 * BATCH * CC * 16;  // floats
    unsigned short* wfb = (unsigned short*)(skip + skipsz);
    float* bfb = (float*)(wfb + WFB_TOTAL);
    unsigned short* wff = (unsigned short*)(bfb + BFB_TOTAL);
    float* bff = (float*)(wff + WFF_TOTAL);

    {
        int tot = WFB_TOTAL + BFB_TOTAL + WFF_TOTAL + BFF_TOTAL;
        fold_kernel<<<(tot + 255) / 256, 256, 0, stream>>>(
            fw_w, fw_b, fw_g, fw_be, fw_m, fw_v,
            bw_w, bw_b, bw_g, bw_be, bw_m, bw_v, c1w, c1b,
            wfb, bfb, wff, bff);
    }

    front_mfma<<<dim3(TT / 256, BATCH, 2), 256, 0, stream>>>(inputs, wff, bff, buf0);

    unsigned short* cur = buf0;
    unsigned short* nxt = buf1;
    for (int i = 0; i < NBLK; ++i) {
        int d = 1 << i;
        int Tt = (d == 128) ? 128 : 256;
        int ntl = TT / Tt;
        int rows_x = Tt + 2 * d;
        int M1 = (Tt + d + 15) >> 4;
        int rows_y1 = M1 << 4;
        size_t lds = ((size_t)(rows_x * CP + 32) + (size_t)(rows_y1 * CP + 32)) * 2 + 4 * 48 * 4;
        block_mfma<<<dim3(ntl, BATCH, 2), 256, lds, stream>>>(
            cur, nxt, wfb, bfb, skip, d, i, Tt, (i < NBLK - 1) ? 1 : 0);
        unsigned short* tmp = cur; cur = nxt; nxt = tmp;
    }

    tail_kernel<<<BATCH, 64, 0, stream>>>(skip, wl, clsw, clsb, (float*)d_out);
}

// Round 4
// 543.319 us; speedup vs baseline: 9.6540x; 1.2109x over previous
//
#include <hip/hip_runtime.h>
#include <math.h>

// Problem constants
#define BATCH 256
#define TT    2048
#define CC    39
#define CP    40        // padded channel stride (bf16) in carried buffers / LDS rows
#define NBLK  8
#define KK    2
#define NCLS  8
#define BN_EPS 1e-5f

typedef __attribute__((ext_vector_type(8))) short short8;
typedef __attribute__((ext_vector_type(4))) float floatx4;

__device__ __forceinline__ unsigned short f2b(float f) {
    union { float f; unsigned u; } v; v.f = f;
    unsigned r = v.u + 0x7FFF + ((v.u >> 16) & 1);   // RNE
    return (unsigned short)(r >> 16);
}
__device__ __forceinline__ unsigned cvtpk(float lo, float hi) {
    unsigned r;
    asm("v_cvt_pk_bf16_f32 %0, %1, %2" : "=v"(r) : "v"(lo), "v"(hi));
    return r;
}
__device__ __forceinline__ float blo(unsigned u) {
    union { unsigned v; float f; } k; k.v = u << 16; return k.f;
}
__device__ __forceinline__ float bhi(unsigned u) {
    union { unsigned v; float f; } k; k.v = u & 0xffff0000u; return k.f;
}

// Weight fragment sizes (A-operand layout: row=co, k=(lane>>4)*8+reg)
#define WFB_PER   (2*3*3*512)          // layer,cotile,slice,lane,reg = 9216
#define WFB_TOTAL (2*NBLK*WFB_PER)     // 147456
#define BFB_TOTAL (2*NBLK*2*48)        // 1536
#define WFF_TOTAL (3*2*512)            // cotile,slice,lane,reg = 3072
#define BFF_TOTAL 48

// ---------------------------------------------------------------------------
// Fold BN into conv weights, baked as MFMA A-operand fragments.
// Block convs: k map per slice s: k<16 -> (p=0, ci=s*16+k); k>=16 -> (p=1, ci=s*16+k-16)
// Front 1x1:   k map per slice s: ci = s*32 + k
// ---------------------------------------------------------------------------
__global__ void fold_kernel(const float* __restrict__ fw_w, const float* __restrict__ fw_b,
                            const float* __restrict__ fw_g, const float* __restrict__ fw_be,
                            const float* __restrict__ fw_m, const float* __restrict__ fw_v,
                            const float* __restrict__ bw_w, const float* __restrict__ bw_b,
                            const float* __restrict__ bw_g, const float* __restrict__ bw_be,
                            const float* __restrict__ bw_m, const float* __restrict__ bw_v,
                            const float* __restrict__ c1w, const float* __restrict__ c1b,
                            unsigned short* __restrict__ wfb, float* __restrict__ bfb,
                            unsigned short* __restrict__ wff, float* __restrict__ bff) {
    int idx = blockIdx.x * blockDim.x + threadIdx.x;
    if (idx < WFB_TOTAL) {
        int i = idx;
        int reg = i & 7;   i >>= 3;
        int lane = i & 63; i >>= 6;
        int sl = i % 3;    i /= 3;
        int ct = i % 3;    i /= 3;
        int layer = i & 1; i >>= 1;
        int blk = i & 7;   i >>= 3;
        int dir = i;
        int co = ct * 16 + (lane & 15);
        int kin = ((lane >> 4) << 3) + reg;     // 0..31
        int p = kin >> 4;
        int ci = sl * 16 + (kin & 15);
        float val = 0.f;
        if (co < CC && ci < CC) {
            const float* w = dir ? bw_w : fw_w;
            const float* g = dir ? bw_g : fw_g;
            const float* v = dir ? bw_v : fw_v;
            int il = blk * 2 + layer;
            float sc = g[il * CC + co] * rsqrtf(v[il * CC + co] + BN_EPS);
            val = w[((size_t)(il * CC + co) * CC + ci) * KK + p] * sc;
        }
        wfb[idx] = f2b(val);
        return;
    }
    idx -= WFB_TOTAL;
    if (idx < BFB_TOTAL) {
        int co = idx % 48;
        int i = idx / 48;
        int layer = i & 1; i >>= 1;
        int blk = i & 7;   i >>= 3;
        int dir = i;
        float val = 0.f;
        if (co < CC) {
            const float* b  = dir ? bw_b  : fw_b;
            const float* g  = dir ? bw_g  : fw_g;
            const float* be = dir ? bw_be : fw_be;
            const float* m  = dir ? bw_m  : fw_m;
            const float* v  = dir ? bw_v  : fw_v;
            int r = (blk * 2 + layer) * CC + co;
            float sc = g[r] * rsqrtf(v[r] + BN_EPS);
            val = (b[r] - m[r]) * sc + be[r];
        }
        bfb[idx] = val;
        return;
    }
    idx -= BFB_TOTAL;
    if (idx < WFF_TOTAL) {
        int i = idx;
        int reg = i & 7;   i >>= 3;
        int lane = i & 63; i >>= 6;
        int sl = i & 1;    i >>= 1;
        int ct = i;        // 0..2
        int co = ct * 16 + (lane & 15);
        int ci = sl * 32 + ((lane >> 4) << 3) + reg;
        float val = (co < CC && ci < CC) ? c1w[co * CC + ci] : 0.f;
        wff[idx] = f2b(val);
        return;
    }
    idx -= WFF_TOTAL;
    if (idx < BFF_TOTAL) {
        bff[idx] = (idx < CC) ? c1b[idx] : 0.f;
    }
}

// ---------------------------------------------------------------------------
// Front: [B,T,C] f32 -> carried [dir][B][T][CP] bf16 via 1x1 conv (MFMA, swapped).
// ---------------------------------------------------------------------------
__global__ __launch_bounds__(256) void front_mfma(const float* __restrict__ in,
                                                  const unsigned short* __restrict__ wf,
                                                  const float* __restrict__ bias,
                                                  unsigned short* __restrict__ out) {
    __shared__ unsigned short xt[256 * CP + 32];
    const int dir = blockIdx.z, b = blockIdx.y, t0 = blockIdx.x * 256;
    const int tid = threadIdx.x, lane = tid & 63, wave = tid >> 6;
    const int c = lane & 15, g = lane >> 4;
    const int stmin = dir ? (TT - t0 - 256) : t0;
    const float* src = in + ((size_t)b * TT + stmin) * CC;

    // stage: [256][39] f32 -> LDS [256][CP] bf16, packed pair-wise
    unsigned* xd = (unsigned*)xt;
    for (int e = tid; e < 256 * 20; e += 256) {
        int row = e / 20, cp = e - row * 20;
        int c0 = cp * 2;
        float f0 = src[(size_t)row * CC + c0];
        float f1 = (c0 + 1 < CC) ? src[(size_t)row * CC + c0 + 1] : 0.f;
        xd[row * 20 + cp] = cvtpk(f0, f1);
    }
    if (tid < 16) ((unsigned*)(xt + 256 * CP))[tid] = 0;    // slack
    __syncthreads();

    short8 Wf[3][2];
#pragma unroll
    for (int ct = 0; ct < 3; ++ct)
#pragma unroll
        for (int sl = 0; sl < 2; ++sl)
            Wf[ct][sl] = *(const short8*)(wf + (((ct * 2 + sl) * 64 + lane) << 3));
    float bs[3][4];
#pragma unroll
    for (int ct = 0; ct < 3; ++ct)
#pragma unroll
        for (int j = 0; j < 4; ++j) bs[ct][j] = bias[ct * 16 + g * 4 + j];

    for (int mt = wave; mt < 16; mt += 4) {
        int row = (mt << 4) + c;
        const unsigned short* bp = xt + row * CP;
        floatx4 acc[3];
#pragma unroll
        for (int ct = 0; ct < 3; ++ct)
            acc[ct] = floatx4{bs[ct][0], bs[ct][1], bs[ct][2], bs[ct][3]};
#pragma unroll
        for (int sl = 0; sl < 2; ++sl) {
            short8 B = *(const short8*)(bp + sl * 32 + g * 8);
#pragma unroll
            for (int ct = 0; ct < 3; ++ct)
                acc[ct] = __builtin_amdgcn_mfma_f32_16x16x32_bf16(Wf[ct][sl], B, acc[ct], 0, 0, 0);
        }
        int t = dir ? (t0 + 255 - row) : (t0 + row);
        unsigned short* op = out + ((size_t)(dir * BATCH + b) * TT + t) * CP;
#pragma unroll
        for (int ct = 0; ct < 3; ++ct) {
            if (ct == 2 && g >= 2) continue;    // co 40..47 don't exist
            uint2 v;
            v.x = cvtpk(acc[ct][0], acc[ct][1]);
            v.y = cvtpk(acc[ct][2], acc[ct][3]);
            *(uint2*)(op + ct * 16 + g * 4) = v;
        }
    }
}

// ---------------------------------------------------------------------------
// One Temporal_Aware_Block, fused, MFMA swapped-operand form.
// ---------------------------------------------------------------------------
__global__ __launch_bounds__(256) void block_mfma(const unsigned short* __restrict__ xg,
                                                  unsigned short* __restrict__ yg,
                                                  const unsigned short* __restrict__ wf_all,
                                                  const float* __restrict__ bf_all,
                                                  float* __restrict__ skipPart,
                                                  int d, int blk, int Tt, int writeOut) {
    extern __shared__ char ldsraw[];
    const int dir = blockIdx.z, b = blockIdx.y, tile = blockIdx.x;
    const int t0 = tile * Tt;
    const int tid = threadIdx.x, lane = tid & 63, wave = tid >> 6;
    const int c = lane & 15, g = lane >> 4;
    const int tapoff = (g >> 1) ? d : 0;        // k>=16 -> tap p=1 (time t)
    const int koff8 = (g & 1) << 3;
    const int rows_x = Tt + 2 * d;
    const int M1 = (Tt + d + 15) >> 4;
    const int rows_y1 = M1 << 4;
    const int rows_real = Tt + d;

    unsigned short* xt = (unsigned short*)ldsraw;             // [rows_x][CP] +32 slack
    unsigned short* y1 = xt + rows_x * CP + 32;               // [rows_y1][CP] +32 slack
    float* stash = (float*)(y1 + rows_y1 * CP + 32);          // [4][48]

    const size_t cbase = (size_t)(dir * BATCH + b) * TT * CP;
    const unsigned short* wf = wf_all + (size_t)(dir * NBLK + blk) * WFB_PER;
    const float* bf = bf_all + (size_t)(dir * NBLK + blk) * 96;

    // ---- load x tile rows [t0-2d, t0+Tt) ----
    {
        const uint4* gsrc = (const uint4*)(xg + cbase);
        uint4* ldst = (uint4*)xt;
        int base_t = t0 - 2 * d;
        int nch = rows_x * 5;                                  // 16B chunks (80B rows)
        for (int ch = tid; ch < nch; ch += 256) {
            int row = ch / 5;
            int t = base_t + row;
            uint4 v;
            if (t < 0) { v.x = v.y = v.z = v.w = 0u; }
            else       { v = gsrc[(size_t)t * 5 + (ch - row * 5)]; }
            ldst[ch] = v;
        }
        if (tid < 16) ((unsigned*)(xt + (size_t)rows_x * CP))[tid] = 0;
        else if (tid < 32) ((unsigned*)(y1 + (size_t)rows_y1 * CP))[tid - 16] = 0;
    }
    __syncthreads();

    // ---- stage 1: y1 = relu(conv1(x)) ----
    short8 Wf[3][3];
#pragma unroll
    for (int ct = 0; ct < 3; ++ct)
#pragma unroll
        for (int sl = 0; sl < 3; ++sl)
            Wf[ct][sl] = *(const short8*)(wf + ((((0 * 3 + ct) * 3 + sl) * 64 + lane) << 3));
    float bs[3][4];
#pragma unroll
    for (int ct = 0; ct < 3; ++ct)
#pragma unroll
        for (int j = 0; j < 4; ++j) bs[ct][j] = bf[ct * 16 + g * 4 + j];

    for (int mt = wave; mt < M1; mt += 4) {
        int j0 = mt << 4;
        int brow = j0 + c + tapoff;
        const unsigned short* bp = xt + brow * CP + koff8;
        floatx4 acc[3];
#pragma unroll
        for (int ct = 0; ct < 3; ++ct)
            acc[ct] = floatx4{bs[ct][0], bs[ct][1], bs[ct][2], bs[ct][3]};
#pragma unroll
        for (int sl = 0; sl < 3; ++sl) {
            short8 B = *(const short8*)(bp + sl * 16);
#pragma unroll
            for (int ct = 0; ct < 3; ++ct)
                acc[ct] = __builtin_amdgcn_mfma_f32_16x16x32_bf16(Wf[ct][sl], B, acc[ct], 0, 0, 0);
        }
        int r = j0 + c;
        bool dead = (t0 - d + r < 0) || (r >= rows_real);
        unsigned short* yp = y1 + r * CP;
#pragma unroll
        for (int ct = 0; ct < 3; ++ct) {
            if (ct == 2 && g >= 2) continue;
            uint2 v;
            v.x = cvtpk(fmaxf(acc[ct][0], 0.f), fmaxf(acc[ct][1], 0.f));
            v.y = cvtpk(fmaxf(acc[ct][2], 0.f), fmaxf(acc[ct][3], 0.f));
            if (dead) { v.x = 0u; v.y = 0u; }
            *(uint2*)(yp + ct * 16 + g * 4) = v;
        }
    }
    __syncthreads();

    // ---- stage 2: y2 = conv2(y1); out = x * sigmoid(y2) ----
#pragma unroll
    for (int ct = 0; ct < 3; ++ct)
#pragma unroll
        for (int sl = 0; sl < 3; ++sl)
            Wf[ct][sl] = *(const short8*)(wf + ((((1 * 3 + ct) * 3 + sl) * 64 + lane) << 3));
#pragma unroll
    for (int ct = 0; ct < 3; ++ct)
#pragma unroll
        for (int j = 0; j < 4; ++j) bs[ct][j] = bf[48 + ct * 16 + g * 4 + j];

    float sums[3][4];
#pragma unroll
    for (int ct = 0; ct < 3; ++ct)
#pragma unroll
        for (int j = 0; j < 4; ++j) sums[ct][j] = 0.f;

    const int M2w = Tt >> 6;
    for (int mi = 0; mi < M2w; ++mi) {
        int j0 = (wave * M2w + mi) << 4;
        int brow = j0 + c + tapoff;
        const unsigned short* bp = y1 + brow * CP + koff8;
        floatx4 acc[3];
#pragma unroll
        for (int ct = 0; ct < 3; ++ct)
            acc[ct] = floatx4{bs[ct][0], bs[ct][1], bs[ct][2], bs[ct][3]};
#pragma unroll
        for (int sl = 0; sl < 3; ++sl) {
            short8 B = *(const short8*)(bp + sl * 16);
#pragma unroll
            for (int ct = 0; ct < 3; ++ct)
                acc[ct] = __builtin_amdgcn_mfma_f32_16x16x32_bf16(Wf[ct][sl], B, acc[ct], 0, 0, 0);
        }
        int r = j0 + c;
        const unsigned short* xrow = xt + (r + 2 * d) * CP;
        unsigned short* orow = yg + cbase + (size_t)(t0 + r) * CP;
#pragma unroll
        for (int ct = 0; ct < 3; ++ct) {
            uint2 xv = *(const uint2*)(xrow + ct * 16 + g * 4);
            float g0 = blo(xv.x) * __builtin_amdgcn_rcpf(1.f + __expf(-acc[ct][0]));
            float g1 = bhi(xv.x) * __builtin_amdgcn_rcpf(1.f + __expf(-acc[ct][1]));
            float g2 = blo(xv.y) * __builtin_amdgcn_rcpf(1.f + __expf(-acc[ct][2]));
            float g3 = bhi(xv.y) * __builtin_amdgcn_rcpf(1.f + __expf(-acc[ct][3]));
            sums[ct][0] += g0; sums[ct][1] += g1;
            sums[ct][2] += g2; sums[ct][3] += g3;
            if (writeOut && !(ct == 2 && g >= 2)) {
                uint2 v;
                v.x = cvtpk(g0, g1);
                v.y = cvtpk(g2, g3);
                *(uint2*)(orow + ct * 16 + g * 4) = v;
            }
        }
    }
    // reduce over the 16 time-cols (lanes differing in bits 0..3)
#pragma unroll
    for (int ct = 0; ct < 3; ++ct)
#pragma unroll
        for (int j = 0; j < 4; ++j) {
            float v = sums[ct][j];
            v += __shfl_xor(v, 1, 64);
            v += __shfl_xor(v, 2, 64);
            v += __shfl_xor(v, 4, 64);
            v += __shfl_xor(v, 8, 64);
            sums[ct][j] = v;
        }
    if (c == 0) {
#pragma unroll
        for (int ct = 0; ct < 3; ++ct)
#pragma unroll
            for (int j = 0; j < 4; ++j)
                stash[wave * 48 + ct * 16 + g * 4 + j] = sums[ct][j];
    }
    __syncthreads();
    if (tid < CC) {
        float s = stash[tid] + stash[48 + tid] + stash[96 + tid] + stash[144 + tid];
        skipPart[(((size_t)(blk * 2 + dir) * BATCH + b) * CC + tid) * 16 + tile] = s;
    }
}

// ---------------------------------------------------------------------------
// Tail: means -> WeightLayer -> classifier -> log_softmax. Block per batch.
// ---------------------------------------------------------------------------
__global__ __launch_bounds__(64) void tail_kernel(const float* __restrict__ skipPart,
                                                  const float* __restrict__ wl,
                                                  const float* __restrict__ cw,
                                                  const float* __restrict__ cb,
                                                  float* __restrict__ out) {
    __shared__ float xs[CC];
    int b = blockIdx.x;
    int cth = threadIdx.x;
    if (cth < CC) {
        float x2 = 0.f;
        for (int i = 0; i < NBLK; ++i) {
            float wli = wl[i] * (1.0f / TT);
            int nt = (i == NBLK - 1) ? 16 : 8;
            for (int dirn = 0; dirn < 2; ++dirn) {
                const float* sp = skipPart + (((size_t)(i * 2 + dirn) * BATCH + b) * CC + cth) * 16;
                float s = 0.f;
                for (int tl = 0; tl < nt; ++tl) s += sp[tl];
                x2 = fmaf(s, wli, x2);
            }
        }
        xs[cth] = x2;
    }
    __syncthreads();
    if (threadIdx.x == 0) {
        float lg[NCLS];
        float mx = -1e30f;
        for (int o = 0; o < NCLS; ++o) {
            float a = cb[o];
#pragma unroll
            for (int cc2 = 0; cc2 < CC; ++cc2) a = fmaf(cw[o * CC + cc2], xs[cc2], a);
            lg[o] = a;
            mx = fmaxf(mx, a);
        }
        float se = 0.f;
        for (int o = 0; o < NCLS; ++o) se += expf(lg[o] - mx);
        float lse = logf(se) + mx;
        for (int o = 0; o < NCLS; ++o) out[b * NCLS + o] = lg[o] - lse;
    }
}

// ---------------------------------------------------------------------------
extern "C" void kernel_launch(void* const* d_in, const int* in_sizes, int n_in,
                              void* d_out, int out_size, void* d_ws, size_t ws_size,
                              hipStream_t stream) {
    const float* inputs = (const float*)d_in[0];
    const float* c1w    = (const float*)d_in[1];
    const float* c1b    = (const float*)d_in[2];
    const float* fw_w   = (const float*)d_in[3];
    const float* fw_b   = (const float*)d_in[4];
    const float* fw_g   = (const float*)d_in[5];
    const float* fw_be  = (const float*)d_in[6];
    const float* fw_m   = (const float*)d_in[7];
    const float* fw_v   = (const float*)d_in[8];
    const float* bw_w   = (const float*)d_in[9];
    const float* bw_b   = (const float*)d_in[10];
    const float* bw_g   = (const float*)d_in[11];
    const float* bw_be  = (const float*)d_in[12];
    const float* bw_m   = (const float*)d_in[13];
    const float* bw_v   = (const float*)d_in[14];
    const float* wl     = (const float*)d_in[15];
    const float* clsw   = (const float*)d_in[16];
    const float* clsb   = (const float*)d_in[17];

    const size_t bufsz = (size_t)2 * BATCH * TT * CP;          // ushorts
    unsigned short* buf0 = (unsigned short*)d_ws;
    unsigned short* buf1 = buf0 + bufsz;
    float* skip = (float*)(buf1 + bufsz);
    const size_t skipsz = (size_t)NBLK * 2 * BATCH * CC * 16;  // floats
    unsigned short* wfb = (unsigned short*)(skip + skipsz);
    float* bfb = (float*)(wfb + WFB_TOTAL);
    unsigned short* wff = (unsigned short*)(bfb + BFB_TOTAL);
    float* bff = (float*)(wff + WFF_TOTAL);

    {
        int tot = WFB_TOTAL + BFB_TOTAL + WFF_TOTAL + BFF_TOTAL;
        fold_kernel<<<(tot + 255) / 256, 256, 0, stream>>>(
            fw_w, fw_b, fw_g, fw_be, fw_m, fw_v,
            bw_w, bw_b, bw_g, bw_be, bw_m, bw_v, c1w, c1b,
            wfb, bfb, wff, bff);
    }

    front_mfma<<<dim3(TT / 256, BATCH, 2), 256, 0, stream>>>(inputs, wff, bff, buf0);

    unsigned short* cur = buf0;
    unsigned short* nxt = buf1;
    for (int i = 0; i < NBLK; ++i) {
        int d = 1 << i;
        int Tt = (d == 128) ? 128 : 256;
        int ntl = TT / Tt;
        int rows_x = Tt + 2 * d;
        int M1 = (Tt + d + 15) >> 4;
        int rows_y1 = M1 << 4;
        size_t lds = ((size_t)(rows_x * CP + 32) + (size_t)(rows_y1 * CP + 32)) * 2 + 4 * 48 * 4;
        block_mfma<<<dim3(ntl, BATCH, 2), 256, lds, stream>>>(
            cur, nxt, wfb, bfb, skip, d, i, Tt, (i < NBLK - 1) ? 1 : 0);
        unsigned short* tmp = cur; cur = nxt; nxt = tmp;
    }

    tail_kernel<<<BATCH, 64, 0, stream>>>(skip, wl, clsw, clsb, (float*)d_out);
}